// Round 1
// baseline (490.892 us; speedup 1.0000x reference)
//
#include <hip/hip_runtime.h>
#include <math.h>

constexpr int kN = 64;     // nodes per batch
constexpr int kF = 13;     // features
constexpr int kD = 128;    // hidden dim
constexpr int kSelf = 6;
constexpr float kTemp = 0.08838834764831845f;  // 1/sqrt(128)

// One block (256 threads = 4 waves) per batch element.
// Thread t: d = t & 127 (output channel), half = t >> 7 (node half: 0 -> nodes 0..31, 1 -> 32..63).
// Wave w covers: w0 = (d 0..63,  nodes 0..31), w1 = (d 64..127, nodes 0..31),
//                w2 = (d 0..63,  nodes 32..63), w3 = (d 64..127, nodes 32..63).
__global__ __launch_bounds__(256) void value_net_kernel(
    const float* __restrict__ state,
    const float* __restrict__ phi1_w, const float* __restrict__ phi1_b,
    const float* __restrict__ phi2_w, const float* __restrict__ phi2_b,
    const float* __restrict__ phi3_w, const float* __restrict__ phi3_b,
    const float* __restrict__ q_w,    const float* __restrict__ q_b,
    const float* __restrict__ k_w,    const float* __restrict__ k_b,
    const float* __restrict__ v_w,    const float* __restrict__ v_b,
    const float* __restrict__ final_w,const float* __restrict__ final_b,
    float* __restrict__ out)
{
  const int b    = blockIdx.x;
  const int tid  = threadIdx.x;
  const int lane = tid & 63;
  const int wave = tid >> 6;
  const int d    = tid & (kD - 1);
  const int half = tid >> 7;
  const int n0   = half * 32;

  __shared__ float s_lds[kN * kF];        // state rows, flat [n*13 + f]
  __shared__ float h3_lds[kN][kD];        // relu(phi3) activations
  __shared__ float qpart[2][kD];          // qsum partials per half
  __shared__ float spart[4][32];          // per-wave score partials
  __shared__ float w_lds[kN];             // softmax weights
  __shared__ float hbar_part[2][kD];
  __shared__ float hbar_lds[kD];
  __shared__ float red[4];

  // ---- P0: stage state row block (coalesced) ----
  const float* sb = state + (size_t)b * (kN * kF);
  for (int i = tid; i < kN * kF; i += 256) s_lds[i] = sb[i];

  // per-thread weight rows (tiny, L2-resident across all 4096 blocks)
  float p3w[kF];
#pragma unroll
  for (int f = 0; f < kF; ++f) p3w[f] = phi3_w[d * kF + f];
  const float b3 = phi3_b[d];
  const float qb = q_b[d];
  const float kb = k_b[d];

  __syncthreads();

  // ---- P1: h3[n][d] = relu(phi3_w[d] . s[n] + b3) ----
#pragma unroll
  for (int n = 0; n < 32; ++n) {
    const float* sr = &s_lds[(n0 + n) * kF];
    float acc = b3;
#pragma unroll
    for (int f = 0; f < kF; ++f) acc = fmaf(p3w[f], sr[f], acc);
    h3_lds[n0 + n][d] = fmaxf(acc, 0.f);
  }
  __syncthreads();

  // ---- P2: q pass: qsum[d] = sum_n relu(q_w[d] . h3[n] + qb) ----
  float qacc[32];
#pragma unroll
  for (int n = 0; n < 32; ++n) qacc[n] = qb;
  for (int kc = 0; kc < 4; ++kc) {
    float4 qw[8];
    const float4* qrow = reinterpret_cast<const float4*>(q_w + d * kD + kc * 32);
#pragma unroll
    for (int j = 0; j < 8; ++j) qw[j] = qrow[j];
#pragma unroll
    for (int n = 0; n < 32; ++n) {
      const float4* hv = reinterpret_cast<const float4*>(&h3_lds[n0 + n][kc * 32]);
#pragma unroll
      for (int j = 0; j < 8; ++j) {
        float4 h = hv[j];   // wave-uniform address -> LDS broadcast
        qacc[n] = fmaf(qw[j].x, h.x, qacc[n]);
        qacc[n] = fmaf(qw[j].y, h.y, qacc[n]);
        qacc[n] = fmaf(qw[j].z, h.z, qacc[n]);
        qacc[n] = fmaf(qw[j].w, h.w, qacc[n]);
      }
    }
  }
  {
    float qp = 0.f;
#pragma unroll
    for (int n = 0; n < 32; ++n) qp += fmaxf(qacc[n], 0.f);
    qpart[half][d] = qp;
  }
  __syncthreads();
  const float qsum_d = qpart[0][d] + qpart[1][d];

  // ---- P3: k pass + score reduction: S[m] = relu(tau * sum_d qsum[d]*relu(k_w[d].h3[m]+kb)) ----
  float kacc[32];
#pragma unroll
  for (int n = 0; n < 32; ++n) kacc[n] = kb;
  for (int kc = 0; kc < 4; ++kc) {
    float4 kw[8];
    const float4* krow = reinterpret_cast<const float4*>(k_w + d * kD + kc * 32);
#pragma unroll
    for (int j = 0; j < 8; ++j) kw[j] = krow[j];
#pragma unroll
    for (int n = 0; n < 32; ++n) {
      const float4* hv = reinterpret_cast<const float4*>(&h3_lds[n0 + n][kc * 32]);
#pragma unroll
      for (int j = 0; j < 8; ++j) {
        float4 h = hv[j];
        kacc[n] = fmaf(kw[j].x, h.x, kacc[n]);
        kacc[n] = fmaf(kw[j].y, h.y, kacc[n]);
        kacc[n] = fmaf(kw[j].z, h.z, kacc[n]);
        kacc[n] = fmaf(kw[j].w, h.w, kacc[n]);
      }
    }
  }
#pragma unroll
  for (int n = 0; n < 32; ++n) {
    float v = qsum_d * fmaxf(kacc[n], 0.f);
#pragma unroll
    for (int off = 32; off > 0; off >>= 1) v += __shfl_xor(v, off, 64);
    if (lane == 0) spart[wave][n] = v;
  }
  __syncthreads();

  // ---- P4: softmax over the 64 scores (wave 0 only) ----
  if (wave == 0) {
    const int m = lane;
    float sc = (m < 32) ? (spart[0][m] + spart[1][m])
                        : (spart[2][m - 32] + spart[3][m - 32]);
    sc = fmaxf(sc * kTemp, 0.f);
    float mx = sc;
#pragma unroll
    for (int off = 32; off > 0; off >>= 1) mx = fmaxf(mx, __shfl_xor(mx, off, 64));
    float e = __expf(sc - mx);
    float s = e;
#pragma unroll
    for (int off = 32; off > 0; off >>= 1) s += __shfl_xor(s, off, 64);
    w_lds[m] = e / s;
  }
  __syncthreads();

  // ---- P5: hbar[d] = sum_m w[m] * relu(phi2_w[d].s[m] + b2)  (h2 recomputed, never stored) ----
  {
    float p2w[kF];
#pragma unroll
    for (int f = 0; f < kF; ++f) p2w[f] = phi2_w[d * kF + f];
    const float b2v = phi2_b[d];
    float hb = 0.f;
#pragma unroll
    for (int n = 0; n < 32; ++n) {
      const float* sr = &s_lds[(n0 + n) * kF];
      float acc = b2v;
#pragma unroll
      for (int f = 0; f < kF; ++f) acc = fmaf(p2w[f], sr[f], acc);
      hb = fmaf(w_lds[n0 + n], fmaxf(acc, 0.f), hb);
    }
    hbar_part[half][d] = hb;
  }
  __syncthreads();
  if (half == 0) hbar_lds[d] = hbar_part[0][d] + hbar_part[1][d];
  __syncthreads();

  // ---- P6: e_g[d] = v_w[d] . hbar + v_b[d]; value = final_w . [e_g, e_h] + final_b ----
  float contrib;
  {
    const float4* vrow = reinterpret_cast<const float4*>(v_w + d * kD + half * 64);
    const float4* hbv  = reinterpret_cast<const float4*>(&hbar_lds[half * 64]);
    float egp = 0.f;
#pragma unroll
    for (int j = 0; j < 16; ++j) {
      float4 w4 = vrow[j];
      float4 h4 = hbv[j];
      egp = fmaf(w4.x, h4.x, egp);
      egp = fmaf(w4.y, h4.y, egp);
      egp = fmaf(w4.z, h4.z, egp);
      egp = fmaf(w4.w, h4.w, egp);
    }
    if (half == 0) egp += v_b[d];
    contrib = final_w[d] * egp;
    if (half == 0) {
      // e_h[d] = phi1_w[d] . state[b,0,:6] + phi1_b[d]
      float eh = phi1_b[d];
#pragma unroll
      for (int j = 0; j < kSelf; ++j) eh = fmaf(phi1_w[d * kSelf + j], s_lds[j], eh);
      contrib = fmaf(final_w[kD + d], eh, contrib);
    }
  }
#pragma unroll
  for (int off = 32; off > 0; off >>= 1) contrib += __shfl_xor(contrib, off, 64);
  if (lane == 0) red[wave] = contrib;
  __syncthreads();
  if (tid == 0) out[b] = red[0] + red[1] + red[2] + red[3] + final_b[0];
}

extern "C" void kernel_launch(void* const* d_in, const int* in_sizes, int n_in,
                              void* d_out, int out_size, void* d_ws, size_t ws_size,
                              hipStream_t stream) {
  const float* state   = (const float*)d_in[0];
  const float* phi1_w  = (const float*)d_in[1];
  const float* phi1_b  = (const float*)d_in[2];
  const float* phi2_w  = (const float*)d_in[3];
  const float* phi2_b  = (const float*)d_in[4];
  const float* phi3_w  = (const float*)d_in[5];
  const float* phi3_b  = (const float*)d_in[6];
  const float* q_w     = (const float*)d_in[7];
  const float* q_b     = (const float*)d_in[8];
  const float* k_w     = (const float*)d_in[9];
  const float* k_b     = (const float*)d_in[10];
  const float* v_w     = (const float*)d_in[11];
  const float* v_b     = (const float*)d_in[12];
  const float* final_w = (const float*)d_in[13];
  const float* final_b = (const float*)d_in[14];
  float* out = (float*)d_out;

  const int batches = in_sizes[0] / (kN * kF);  // 4096
  value_net_kernel<<<dim3(batches), dim3(256), 0, stream>>>(
      state, phi1_w, phi1_b, phi2_w, phi2_b, phi3_w, phi3_b,
      q_w, q_b, k_w, k_b, v_w, v_b, final_w, final_b, out);
}

// Round 2
// 174.797 us; speedup vs baseline: 2.8083x; 2.8083x over previous
//
#include <hip/hip_runtime.h>
#include <math.h>

typedef __attribute__((ext_vector_type(8))) short short8;
typedef __attribute__((ext_vector_type(4))) float f32x4;

constexpr int kN = 64;     // nodes per batch
constexpr int kF = 13;     // features
constexpr int kD = 128;    // hidden dim
constexpr int kSelf = 6;
constexpr float kTemp = 0.08838834764831845f;  // 1/sqrt(128)

__device__ __forceinline__ ushort bf16_rne(float f) {
  union { float f; uint32_t u; } v; v.f = f;
  uint32_t u = v.u;
  return (ushort)((u + 0x7fffu + ((u >> 16) & 1u)) >> 16);
}
__device__ __forceinline__ float bf16_f32(ushort h) {
  union { uint32_t u; float f; } v; v.u = ((uint32_t)h) << 16;
  return v.f;
}

// Load one B-operand fragment (8 consecutive k of weight row `drow`) as split bf16.
// Fragment element i must be W[drow][ks*32 + g*8 + i]  (B[k][col] layout: col=lane&15 -> drow, k=(lane>>4)*8+i).
__device__ __forceinline__ void load_wfrag(const float* __restrict__ W, int drow, int ks, int g,
                                           short8* hi, short8* lo) {
  const float* p = W + drow * kD + ks * 32 + g * 8;
  float4 x0 = *(const float4*)p;
  float4 x1 = *(const float4*)(p + 4);
  float xs[8] = {x0.x, x0.y, x0.z, x0.w, x1.x, x1.y, x1.z, x1.w};
  short8 h, l;
#pragma unroll
  for (int i = 0; i < 8; ++i) {
    ushort hb = bf16_rne(xs[i]);
    h[i] = (short)hb;
    l[i] = (short)bf16_rne(xs[i] - bf16_f32(hb));
  }
  *hi = h; *lo = l;
}

// One block (256 threads = 4 waves) per batch element.
// Wave w owns output channels d in [32w, 32w+32) for the Q/K MFMA passes.
__global__ __launch_bounds__(256) void value_net_kernel(
    const float* __restrict__ state,
    const float* __restrict__ phi1_w, const float* __restrict__ phi1_b,
    const float* __restrict__ phi2_w, const float* __restrict__ phi2_b,
    const float* __restrict__ phi3_w, const float* __restrict__ phi3_b,
    const float* __restrict__ q_w,    const float* __restrict__ q_b,
    const float* __restrict__ k_w,    const float* __restrict__ k_b,
    const float* __restrict__ v_w,    const float* __restrict__ v_b,
    const float* __restrict__ final_w,const float* __restrict__ final_b,
    float* __restrict__ out)
{
  const int b    = blockIdx.x;
  const int tid  = threadIdx.x;
  const int lane = tid & 63;
  const int wave = tid >> 6;
  const int d    = tid & (kD - 1);
  const int half = tid >> 7;
  const int n0   = half * 32;
  const int lc   = lane & 15;   // fragment col
  const int lg   = lane >> 4;   // fragment k-group / row-group

  __shared__ float s_lds[kN * kF];
  __shared__ __align__(16) ushort h3_hi[kN * kD];  // swizzled split bf16 of h3
  __shared__ __align__(16) ushort h3_lo[kN * kD];
  __shared__ float spart[4][kN];
  __shared__ float w_lds[kN];
  __shared__ float hbar_part[2][kD];
  __shared__ float hbar_lds[kD];
  __shared__ float red[4];

  // ---- stage state rows (coalesced) ----
  const float* sb = state + (size_t)b * (kN * kF);
  for (int i = tid; i < kN * kF; i += 256) s_lds[i] = sb[i];

  // per-thread phi3 row
  float p3w[kF];
#pragma unroll
  for (int f = 0; f < kF; ++f) p3w[f] = phi3_w[d * kF + f];
  const float b3 = phi3_b[d];

  // ---- per-lane Q-weight fragments + biases (global loads, independent of LDS) ----
  const int dbase = wave * 32;
  float qbv[2], kbv[2];
  short8 bqh[2][4], bql[2][4];
#pragma unroll
  for (int dtl = 0; dtl < 2; ++dtl) {
    const int drow = dbase + dtl * 16 + lc;
    qbv[dtl] = q_b[drow];
    kbv[dtl] = k_b[drow];
#pragma unroll
    for (int ks = 0; ks < 4; ++ks)
      load_wfrag(q_w, drow, ks, lg, &bqh[dtl][ks], &bql[dtl][ks]);
  }

  __syncthreads();  // s_lds ready

  // ---- phi3: h3[n][d] = relu(phi3_w[d].s[n]+b3), stored as split bf16, swizzled ----
#pragma unroll
  for (int n = 0; n < 32; ++n) {
    const int nn = n0 + n;
    const float* sr = &s_lds[nn * kF];
    float acc = b3;
#pragma unroll
    for (int f = 0; f < kF; ++f) acc = fmaf(p3w[f], sr[f], acc);
    acc = fmaxf(acc, 0.f);
    const ushort hb = bf16_rne(acc);
    const ushort lb = bf16_rne(acc - bf16_f32(hb));
    const int idx = (nn * kD + d) ^ ((nn & 7) << 3);
    h3_hi[idx] = hb;
    h3_lo[idx] = lb;
  }
  __syncthreads();  // h3 ready

  // ---- Q pass: qsum[d] = sum_n relu(Q[n][d]+qb), kept in-lane ----
  float qs[2] = {0.f, 0.f};
#pragma unroll
  for (int nt = 0; nt < 4; ++nt) {
    const int row = nt * 16 + lc;
    short8 ah[4], al[4];
#pragma unroll
    for (int ks = 0; ks < 4; ++ks) {
      const int idx = (row * kD + ks * 32 + lg * 8) ^ ((row & 7) << 3);
      ah[ks] = *(const short8*)&h3_hi[idx];
      al[ks] = *(const short8*)&h3_lo[idx];
    }
#pragma unroll
    for (int dtl = 0; dtl < 2; ++dtl) {
      f32x4 acc = {0.f, 0.f, 0.f, 0.f};
#pragma unroll
      for (int ks = 0; ks < 4; ++ks) {
        acc = __builtin_amdgcn_mfma_f32_16x16x32_bf16(ah[ks], bqh[dtl][ks], acc, 0, 0, 0);
        acc = __builtin_amdgcn_mfma_f32_16x16x32_bf16(al[ks], bqh[dtl][ks], acc, 0, 0, 0);
        acc = __builtin_amdgcn_mfma_f32_16x16x32_bf16(ah[ks], bql[dtl][ks], acc, 0, 0, 0);
      }
      float t = 0.f;
#pragma unroll
      for (int r = 0; r < 4; ++r) t += fmaxf(acc[r] + qbv[dtl], 0.f);
      qs[dtl] += t;
    }
  }
  // reduce over the 4 row-groups (nodes) -> full qsum for this lane's d
#pragma unroll
  for (int dtl = 0; dtl < 2; ++dtl) {
    qs[dtl] += __shfl_xor(qs[dtl], 16, 64);
    qs[dtl] += __shfl_xor(qs[dtl], 32, 64);
  }

  // ---- K-weight fragments ----
  short8 bkh[2][4], bkl[2][4];
#pragma unroll
  for (int dtl = 0; dtl < 2; ++dtl) {
    const int drow = dbase + dtl * 16 + lc;
#pragma unroll
    for (int ks = 0; ks < 4; ++ks)
      load_wfrag(k_w, drow, ks, lg, &bkh[dtl][ks], &bkl[dtl][ks]);
  }

  // ---- K pass + score partials: spart[w][m] = sum_{d in wave} qsum[d]*relu(K[m][d]+kb) ----
#pragma unroll
  for (int nt = 0; nt < 4; ++nt) {
    const int row = nt * 16 + lc;
    short8 ah[4], al[4];
#pragma unroll
    for (int ks = 0; ks < 4; ++ks) {
      const int idx = (row * kD + ks * 32 + lg * 8) ^ ((row & 7) << 3);
      ah[ks] = *(const short8*)&h3_hi[idx];
      al[ks] = *(const short8*)&h3_lo[idx];
    }
    float pr[4] = {0.f, 0.f, 0.f, 0.f};
#pragma unroll
    for (int dtl = 0; dtl < 2; ++dtl) {
      f32x4 acc = {0.f, 0.f, 0.f, 0.f};
#pragma unroll
      for (int ks = 0; ks < 4; ++ks) {
        acc = __builtin_amdgcn_mfma_f32_16x16x32_bf16(ah[ks], bkh[dtl][ks], acc, 0, 0, 0);
        acc = __builtin_amdgcn_mfma_f32_16x16x32_bf16(al[ks], bkh[dtl][ks], acc, 0, 0, 0);
        acc = __builtin_amdgcn_mfma_f32_16x16x32_bf16(ah[ks], bkl[dtl][ks], acc, 0, 0, 0);
      }
#pragma unroll
      for (int r = 0; r < 4; ++r)
        pr[r] = fmaf(qs[dtl], fmaxf(acc[r] + kbv[dtl], 0.f), pr[r]);
    }
    // reduce over the 16 cols (d) of this wave's d-range
#pragma unroll
    for (int r = 0; r < 4; ++r) {
      pr[r] += __shfl_xor(pr[r], 1, 64);
      pr[r] += __shfl_xor(pr[r], 2, 64);
      pr[r] += __shfl_xor(pr[r], 4, 64);
      pr[r] += __shfl_xor(pr[r], 8, 64);
    }
    if (lc == 0) {
#pragma unroll
      for (int r = 0; r < 4; ++r) spart[wave][nt * 16 + lg * 4 + r] = pr[r];
    }
  }
  __syncthreads();

  // ---- softmax over the 64 scores (wave 0) ----
  if (wave == 0) {
    const int m = lane;
    float sc = spart[0][m] + spart[1][m] + spart[2][m] + spart[3][m];
    sc = fmaxf(sc * kTemp, 0.f);
    float mx = sc;
#pragma unroll
    for (int off = 32; off > 0; off >>= 1) mx = fmaxf(mx, __shfl_xor(mx, off, 64));
    float e = __expf(sc - mx);
    float s = e;
#pragma unroll
    for (int off = 32; off > 0; off >>= 1) s += __shfl_xor(s, off, 64);
    w_lds[m] = e / s;
  }
  __syncthreads();

  // ---- hbar[d] = sum_m w[m]*relu(phi2_w[d].s[m]+b2) (h2 recomputed, never stored) ----
  {
    float p2w[kF];
#pragma unroll
    for (int f = 0; f < kF; ++f) p2w[f] = phi2_w[d * kF + f];
    const float b2v = phi2_b[d];
    float hb = 0.f;
#pragma unroll
    for (int n = 0; n < 32; ++n) {
      const float* sr = &s_lds[(n0 + n) * kF];
      float acc = b2v;
#pragma unroll
      for (int f = 0; f < kF; ++f) acc = fmaf(p2w[f], sr[f], acc);
      hb = fmaf(w_lds[n0 + n], fmaxf(acc, 0.f), hb);
    }
    hbar_part[half][d] = hb;
  }
  __syncthreads();
  if (half == 0) hbar_lds[d] = hbar_part[0][d] + hbar_part[1][d];
  __syncthreads();

  // ---- e_g = v_w . hbar + v_b; value = final_w . [e_g, e_h] + final_b ----
  float contrib;
  {
    const float4* vrow = reinterpret_cast<const float4*>(v_w + d * kD + half * 64);
    const float4* hbv  = reinterpret_cast<const float4*>(&hbar_lds[half * 64]);
    float egp = 0.f;
#pragma unroll
    for (int j = 0; j < 16; ++j) {
      float4 w4 = vrow[j];
      float4 h4 = hbv[j];
      egp = fmaf(w4.x, h4.x, egp);
      egp = fmaf(w4.y, h4.y, egp);
      egp = fmaf(w4.z, h4.z, egp);
      egp = fmaf(w4.w, h4.w, egp);
    }
    if (half == 0) egp += v_b[d];
    contrib = final_w[d] * egp;
    if (half == 0) {
      float eh = phi1_b[d];
#pragma unroll
      for (int j = 0; j < kSelf; ++j) eh = fmaf(phi1_w[d * kSelf + j], s_lds[j], eh);
      contrib = fmaf(final_w[kD + d], eh, contrib);
    }
  }
#pragma unroll
  for (int off = 32; off > 0; off >>= 1) contrib += __shfl_xor(contrib, off, 64);
  if (lane == 0) red[wave] = contrib;
  __syncthreads();
  if (tid == 0) out[b] = red[0] + red[1] + red[2] + red[3] + final_b[0];
}

extern "C" void kernel_launch(void* const* d_in, const int* in_sizes, int n_in,
                              void* d_out, int out_size, void* d_ws, size_t ws_size,
                              hipStream_t stream) {
  const float* state   = (const float*)d_in[0];
  const float* phi1_w  = (const float*)d_in[1];
  const float* phi1_b  = (const float*)d_in[2];
  const float* phi2_w  = (const float*)d_in[3];
  const float* phi2_b  = (const float*)d_in[4];
  const float* phi3_w  = (const float*)d_in[5];
  const float* phi3_b  = (const float*)d_in[6];
  const float* q_w     = (const float*)d_in[7];
  const float* q_b     = (const float*)d_in[8];
  const float* k_w     = (const float*)d_in[9];
  const float* k_b     = (const float*)d_in[10];
  const float* v_w     = (const float*)d_in[11];
  const float* v_b     = (const float*)d_in[12];
  const float* final_w = (const float*)d_in[13];
  const float* final_b = (const float*)d_in[14];
  float* out = (float*)d_out;

  const int batches = in_sizes[0] / (kN * kF);  // 4096
  value_net_kernel<<<dim3(batches), dim3(256), 0, stream>>>(
      state, phi1_w, phi1_b, phi2_w, phi2_b, phi3_w, phi3_b,
      q_w, q_b, k_w, k_b, v_w, v_b, final_w, final_b, out);
}

// Round 3
// 155.866 us; speedup vs baseline: 3.1494x; 1.1215x over previous
//
#include <hip/hip_runtime.h>
#include <math.h>

typedef __attribute__((ext_vector_type(8))) short short8;
typedef __attribute__((ext_vector_type(4))) float f32x4;

constexpr int kN = 64;     // nodes per batch
constexpr int kF = 13;     // features
constexpr int kD = 128;    // hidden dim
constexpr int kSelf = 6;
constexpr float kTemp = 0.08838834764831845f;  // 1/sqrt(128)

// ws layout (ushort element offsets)
constexpr int WS_QH  = 0;
constexpr int WS_QL  = 16384;
constexpr int WS_KH  = 32768;
constexpr int WS_KL  = 49152;
constexpr int WS_P3H = 65536;   // phi3 padded rows [128][32]
constexpr int WS_P3L = 69632;
constexpr int WS_P2H = 73728;
constexpr int WS_P2L = 77824;
// total 81920 ushorts = 160 KB

__device__ __forceinline__ ushort bf16_rne(float f) {
  union { float f; uint32_t u; } v; v.f = f;
  uint32_t u = v.u;
  return (ushort)((u + 0x7fffu + ((u >> 16) & 1u)) >> 16);
}
__device__ __forceinline__ float bf16_f32(ushort h) {
  union { uint32_t u; float f; } v; v.u = ((uint32_t)h) << 16;
  return v.f;
}

// Pre-split all weight matrices into bf16 hi/lo planes (identical for every block,
// so do it once per launch instead of once per block).
__global__ __launch_bounds__(256) void prep_kernel(
    const float* __restrict__ q_w, const float* __restrict__ k_w,
    const float* __restrict__ p3w, const float* __restrict__ p2w,
    ushort* __restrict__ ws)
{
  const int i = blockIdx.x * 256 + threadIdx.x;
  if (i < 16384) {
    float v = q_w[i]; ushort h = bf16_rne(v);
    ws[WS_QH + i] = h; ws[WS_QL + i] = bf16_rne(v - bf16_f32(h));
  } else if (i < 32768) {
    int j = i - 16384; float v = k_w[j]; ushort h = bf16_rne(v);
    ws[WS_KH + j] = h; ws[WS_KL + j] = bf16_rne(v - bf16_f32(h));
  } else if (i < 36864) {
    int j = i - 32768; int dd = j >> 5, kk = j & 31;
    float v = (kk < kF) ? p3w[dd * kF + kk] : 0.f;
    ushort h = bf16_rne(v);
    ws[WS_P3H + j] = h; ws[WS_P3L + j] = bf16_rne(v - bf16_f32(h));
  } else if (i < 40960) {
    int j = i - 36864; int dd = j >> 5, kk = j & 31;
    float v = (kk < kF) ? p2w[dd * kF + kk] : 0.f;
    ushort h = bf16_rne(v);
    ws[WS_P2H + j] = h; ws[WS_P2L + j] = bf16_rne(v - bf16_f32(h));
  }
}

// One block (256 threads = 4 waves) per batch element.
__global__ __launch_bounds__(256) void value_net_kernel(
    const float* __restrict__ state,
    const float* __restrict__ phi1_w, const float* __restrict__ phi1_b,
    const float* __restrict__ phi2_b, const float* __restrict__ phi3_b,
    const float* __restrict__ q_b,    const float* __restrict__ k_b,
    const float* __restrict__ v_w,    const float* __restrict__ v_b,
    const float* __restrict__ final_w,const float* __restrict__ final_b,
    const ushort* __restrict__ wsc,
    float* __restrict__ out)
{
  const int b    = blockIdx.x;
  const int tid  = threadIdx.x;
  const int lane = tid & 63;
  const int wave = tid >> 6;
  const int d    = tid & (kD - 1);
  const int half = tid >> 7;
  const int lc   = lane & 15;   // fragment col
  const int lg   = lane >> 4;   // fragment k-group / row-group

  __shared__ float s_lds[kN][16];                  // state rows, padded 13->16 (zero tail)
  __shared__ __align__(16) ushort h3_hi[kN * kD];  // swizzled split bf16 of h3
  __shared__ __align__(16) ushort h3_lo[kN * kD];
  __shared__ float spart[4][kN];
  __shared__ float w_lds[kN];
  __shared__ float hbar_w[4][kD];
  __shared__ float hbar_lds[kD];
  __shared__ float red[4];

  // ---- stage state rows (coalesced) + zero pad ----
  const float* sb = state + (size_t)b * (kN * kF);
  for (int i = tid; i < kN * kF; i += 256) s_lds[i / kF][i % kF] = sb[i];
  for (int i = tid; i < kN * 3; i += 256) s_lds[i / 3][kF + (i % 3)] = 0.f;
  __syncthreads();

  // ---- A-fragments of state (split bf16), shared by phi3 and phi2 MFMAs ----
  // A[row = lane&15][k = lg*8+i]; rows = this wave's 16 nodes; k>=16 is zero pad.
  short8 a3h = {0, 0, 0, 0, 0, 0, 0, 0};
  short8 a3l = {0, 0, 0, 0, 0, 0, 0, 0};
  if (lg < 2) {
    const float* p = &s_lds[wave * 16 + lc][lg * 8];
#pragma unroll
    for (int i = 0; i < 8; ++i) {
      float x = p[i];
      ushort hbv = bf16_rne(x);
      a3h[i] = (short)hbv;
      a3l[i] = (short)bf16_rne(x - bf16_f32(hbv));
    }
  }

  // ---- phi3 via MFMA: h3[n][d] = relu(state @ phi3_w^T + b3), split bf16 to LDS ----
#pragma unroll
  for (int nt = 0; nt < 8; ++nt) {
    const int dcol = nt * 16 + lc;
    short8 bh = *(const short8*)&wsc[WS_P3H + dcol * 32 + lg * 8];
    short8 bl = *(const short8*)&wsc[WS_P3L + dcol * 32 + lg * 8];
    f32x4 a = {0.f, 0.f, 0.f, 0.f};
    a = __builtin_amdgcn_mfma_f32_16x16x32_bf16(a3h, bh, a, 0, 0, 0);
    a = __builtin_amdgcn_mfma_f32_16x16x32_bf16(a3l, bh, a, 0, 0, 0);
    a = __builtin_amdgcn_mfma_f32_16x16x32_bf16(a3h, bl, a, 0, 0, 0);
    const float bias = phi3_b[dcol];
#pragma unroll
    for (int r = 0; r < 4; ++r) {
      const int nw = wave * 16 + lg * 4 + r;
      float v = fmaxf(a[r] + bias, 0.f);
      ushort hbv = bf16_rne(v);
      ushort lbv = bf16_rne(v - bf16_f32(hbv));
      const int idx = (nw * kD + dcol) ^ ((nw & 7) << 3);
      h3_hi[idx] = hbv;
      h3_lo[idx] = lbv;
    }
  }
  __syncthreads();  // h3 ready

  const int dbase = wave * 32;

  // ---- Q pass: qsum[d] = sum_n relu(Q[n][d]+qb), kept in-lane ----
  float qs[2] = {0.f, 0.f};
  {
    const float qbv[2] = {q_b[dbase + lc], q_b[dbase + 16 + lc]};
    short8 bqh[2][4], bql[2][4];
#pragma unroll
    for (int dtl = 0; dtl < 2; ++dtl) {
      const int drow = dbase + dtl * 16 + lc;
#pragma unroll
      for (int ks = 0; ks < 4; ++ks) {
        bqh[dtl][ks] = *(const short8*)&wsc[WS_QH + drow * kD + ks * 32 + lg * 8];
        bql[dtl][ks] = *(const short8*)&wsc[WS_QL + drow * kD + ks * 32 + lg * 8];
      }
    }
#pragma unroll
    for (int nt = 0; nt < 4; ++nt) {
      const int row = nt * 16 + lc;
      short8 ah[4], al[4];
#pragma unroll
      for (int ks = 0; ks < 4; ++ks) {
        const int idx = (row * kD + ks * 32 + lg * 8) ^ ((row & 7) << 3);
        ah[ks] = *(const short8*)&h3_hi[idx];
        al[ks] = *(const short8*)&h3_lo[idx];
      }
#pragma unroll
      for (int dtl = 0; dtl < 2; ++dtl) {
        f32x4 acc = {0.f, 0.f, 0.f, 0.f};
#pragma unroll
        for (int ks = 0; ks < 4; ++ks) {
          acc = __builtin_amdgcn_mfma_f32_16x16x32_bf16(ah[ks], bqh[dtl][ks], acc, 0, 0, 0);
          acc = __builtin_amdgcn_mfma_f32_16x16x32_bf16(al[ks], bqh[dtl][ks], acc, 0, 0, 0);
          acc = __builtin_amdgcn_mfma_f32_16x16x32_bf16(ah[ks], bql[dtl][ks], acc, 0, 0, 0);
        }
        float t = 0.f;
#pragma unroll
        for (int r = 0; r < 4; ++r) t += fmaxf(acc[r] + qbv[dtl], 0.f);
        qs[dtl] += t;
      }
    }
  }
#pragma unroll
  for (int dtl = 0; dtl < 2; ++dtl) {
    qs[dtl] += __shfl_xor(qs[dtl], 16, 64);
    qs[dtl] += __shfl_xor(qs[dtl], 32, 64);
  }

  // ---- K pass + score partials ----
  {
    const float kbv[2] = {k_b[dbase + lc], k_b[dbase + 16 + lc]};
    short8 bkh[2][4], bkl[2][4];
#pragma unroll
    for (int dtl = 0; dtl < 2; ++dtl) {
      const int drow = dbase + dtl * 16 + lc;
#pragma unroll
      for (int ks = 0; ks < 4; ++ks) {
        bkh[dtl][ks] = *(const short8*)&wsc[WS_KH + drow * kD + ks * 32 + lg * 8];
        bkl[dtl][ks] = *(const short8*)&wsc[WS_KL + drow * kD + ks * 32 + lg * 8];
      }
    }
#pragma unroll
    for (int nt = 0; nt < 4; ++nt) {
      const int row = nt * 16 + lc;
      short8 ah[4], al[4];
#pragma unroll
      for (int ks = 0; ks < 4; ++ks) {
        const int idx = (row * kD + ks * 32 + lg * 8) ^ ((row & 7) << 3);
        ah[ks] = *(const short8*)&h3_hi[idx];
        al[ks] = *(const short8*)&h3_lo[idx];
      }
      float pr[4] = {0.f, 0.f, 0.f, 0.f};
#pragma unroll
      for (int dtl = 0; dtl < 2; ++dtl) {
        f32x4 acc = {0.f, 0.f, 0.f, 0.f};
#pragma unroll
        for (int ks = 0; ks < 4; ++ks) {
          acc = __builtin_amdgcn_mfma_f32_16x16x32_bf16(ah[ks], bkh[dtl][ks], acc, 0, 0, 0);
          acc = __builtin_amdgcn_mfma_f32_16x16x32_bf16(al[ks], bkh[dtl][ks], acc, 0, 0, 0);
          acc = __builtin_amdgcn_mfma_f32_16x16x32_bf16(ah[ks], bkl[dtl][ks], acc, 0, 0, 0);
        }
#pragma unroll
        for (int r = 0; r < 4; ++r)
          pr[r] = fmaf(qs[dtl], fmaxf(acc[r] + kbv[dtl], 0.f), pr[r]);
      }
#pragma unroll
      for (int r = 0; r < 4; ++r) {
        pr[r] += __shfl_xor(pr[r], 1, 64);
        pr[r] += __shfl_xor(pr[r], 2, 64);
        pr[r] += __shfl_xor(pr[r], 4, 64);
        pr[r] += __shfl_xor(pr[r], 8, 64);
      }
      if (lc == 0) {
#pragma unroll
        for (int r = 0; r < 4; ++r) spart[wave][nt * 16 + lg * 4 + r] = pr[r];
      }
    }
  }
  __syncthreads();

  // ---- softmax over the 64 scores (wave 0) ----
  if (wave == 0) {
    const int m = lane;
    float sc = spart[0][m] + spart[1][m] + spart[2][m] + spart[3][m];
    sc = fmaxf(sc * kTemp, 0.f);
    float mx = sc;
#pragma unroll
    for (int off = 32; off > 0; off >>= 1) mx = fmaxf(mx, __shfl_xor(mx, off, 64));
    float e = __expf(sc - mx);
    float s = e;
#pragma unroll
    for (int off = 32; off > 0; off >>= 1) s += __shfl_xor(s, off, 64);
    w_lds[m] = e / s;
  }
  __syncthreads();

  // ---- phi2 via MFMA (epilogue): hbar[d] = sum_n w[n]*relu(h2[n][d]) ----
  {
    float wv[4];
#pragma unroll
    for (int r = 0; r < 4; ++r) wv[r] = w_lds[wave * 16 + lg * 4 + r];
#pragma unroll
    for (int nt = 0; nt < 8; ++nt) {
      const int dcol = nt * 16 + lc;
      short8 bh = *(const short8*)&wsc[WS_P2H + dcol * 32 + lg * 8];
      short8 bl = *(const short8*)&wsc[WS_P2L + dcol * 32 + lg * 8];
      f32x4 a = {0.f, 0.f, 0.f, 0.f};
      a = __builtin_amdgcn_mfma_f32_16x16x32_bf16(a3h, bh, a, 0, 0, 0);
      a = __builtin_amdgcn_mfma_f32_16x16x32_bf16(a3l, bh, a, 0, 0, 0);
      a = __builtin_amdgcn_mfma_f32_16x16x32_bf16(a3h, bl, a, 0, 0, 0);
      const float b2 = phi2_b[dcol];
      float hp = 0.f;
#pragma unroll
      for (int r = 0; r < 4; ++r) hp = fmaf(wv[r], fmaxf(a[r] + b2, 0.f), hp);
      hp += __shfl_xor(hp, 16, 64);
      hp += __shfl_xor(hp, 32, 64);
      if (lg == 0) hbar_w[wave][dcol] = hp;
    }
  }
  __syncthreads();
  if (half == 0) hbar_lds[d] = hbar_w[0][d] + hbar_w[1][d] + hbar_w[2][d] + hbar_w[3][d];
  __syncthreads();

  // ---- e_g = v_w . hbar + v_b; value = final_w . [e_g, e_h] + final_b ----
  float contrib;
  {
    const float4* vrow = reinterpret_cast<const float4*>(v_w + d * kD + half * 64);
    const float4* hbv  = reinterpret_cast<const float4*>(&hbar_lds[half * 64]);
    float egp = 0.f;
#pragma unroll
    for (int j = 0; j < 16; ++j) {
      float4 w4 = vrow[j];
      float4 h4 = hbv[j];
      egp = fmaf(w4.x, h4.x, egp);
      egp = fmaf(w4.y, h4.y, egp);
      egp = fmaf(w4.z, h4.z, egp);
      egp = fmaf(w4.w, h4.w, egp);
    }
    if (half == 0) egp += v_b[d];
    contrib = final_w[d] * egp;
    if (half == 0) {
      float eh = phi1_b[d];
#pragma unroll
      for (int j = 0; j < kSelf; ++j) eh = fmaf(phi1_w[d * kSelf + j], s_lds[0][j], eh);
      contrib = fmaf(final_w[kD + d], eh, contrib);
    }
  }
#pragma unroll
  for (int off = 32; off > 0; off >>= 1) contrib += __shfl_xor(contrib, off, 64);
  if (lane == 0) red[wave] = contrib;
  __syncthreads();
  if (tid == 0) out[b] = red[0] + red[1] + red[2] + red[3] + final_b[0];
}

extern "C" void kernel_launch(void* const* d_in, const int* in_sizes, int n_in,
                              void* d_out, int out_size, void* d_ws, size_t ws_size,
                              hipStream_t stream) {
  const float* state   = (const float*)d_in[0];
  const float* phi1_w  = (const float*)d_in[1];
  const float* phi1_b  = (const float*)d_in[2];
  const float* phi2_w  = (const float*)d_in[3];
  const float* phi2_b  = (const float*)d_in[4];
  const float* phi3_w  = (const float*)d_in[5];
  const float* phi3_b  = (const float*)d_in[6];
  const float* q_w     = (const float*)d_in[7];
  const float* q_b     = (const float*)d_in[8];
  const float* k_w     = (const float*)d_in[9];
  const float* k_b     = (const float*)d_in[10];
  const float* v_w     = (const float*)d_in[11];
  const float* v_b     = (const float*)d_in[12];
  const float* final_w = (const float*)d_in[13];
  const float* final_b = (const float*)d_in[14];
  float* out = (float*)d_out;
  ushort* ws = (ushort*)d_ws;

  prep_kernel<<<dim3(160), dim3(256), 0, stream>>>(q_w, k_w, phi3_w, phi2_w, ws);

  const int batches = in_sizes[0] / (kN * kF);  // 4096
  value_net_kernel<<<dim3(batches), dim3(256), 0, stream>>>(
      state, phi1_w, phi1_b, phi2_b, phi3_b,
      q_b, k_b, v_w, v_b, final_w, final_b, ws, out);
}

// Round 4
// 104.854 us; speedup vs baseline: 4.6817x; 1.4865x over previous
//
#include <hip/hip_runtime.h>
#include <math.h>

typedef __attribute__((ext_vector_type(8))) short short8;
typedef __attribute__((ext_vector_type(4))) float f32x4;

constexpr int kN = 64;     // nodes per batch
constexpr int kF = 13;     // features
constexpr int kD = 128;    // hidden dim
constexpr int kSelf = 6;
constexpr float kTemp = 0.08838834764831845f;  // 1/sqrt(128)

// ws layout. All weight planes are FRAGMENT-PACKED in lane order:
// chunk = 512 ushorts (64 lanes x 8 bf16 = 1KB), so a wave's fragment load is
// base + lane*16B -> one coalesced transaction (no 16-line gather).
// Q/K planes: 32 chunks, chunk c = (dtile 0..7)*4 + ks; lane l=(lg<<4)|lc;
//   elem e: W[dtile*16+lc][ks*32+lg*8+e]
// phi planes: 8 chunks (nt 0..7): P[nt*16+lc][lg*8+e] (k>=13 zero-padded)
// v plane (f32, after ushort region): 32 chunks of 512 f32, chunk j4:
//   entry d*4+jj = v_w[d][j4*4+jj]
constexpr int WS_QH  = 0;
constexpr int WS_QL  = 16384;
constexpr int WS_KH  = 32768;
constexpr int WS_KL  = 49152;
constexpr int WS_P3H = 65536;
constexpr int WS_P3L = 69632;
constexpr int WS_P2H = 73728;
constexpr int WS_P2L = 77824;
constexpr int WS_USH_END = 81920;       // ushorts (163840 B)
// f32 v region: [WS_USH_END ushorts .. +16384 f32] -> total 229376 B

__device__ __forceinline__ ushort bf16_rne(float f) {
  union { float f; uint32_t u; } v; v.f = f;
  uint32_t u = v.u;
  return (ushort)((u + 0x7fffu + ((u >> 16) & 1u)) >> 16);
}
__device__ __forceinline__ float bf16_f32(ushort h) {
  union { uint32_t u; float f; } v; v.u = ((uint32_t)h) << 16;
  return v.f;
}

__global__ __launch_bounds__(256) void prep_kernel(
    const float* __restrict__ q_w, const float* __restrict__ k_w,
    const float* __restrict__ p3w, const float* __restrict__ p2w,
    const float* __restrict__ v_w,
    ushort* __restrict__ ws)
{
  const int i = blockIdx.x * 256 + threadIdx.x;
  if (i < 32768) {  // Q (0..16383) / K (16384..32767) fragment planes
    const int j = i & 16383;
    const bool isQ = i < 16384;
    const int c  = j >> 9;          // (dtile<<2)|ks
    const int l  = (j >> 3) & 63;
    const int e  = j & 7;
    const int lc = l & 15, lg = l >> 4;
    const int drow = (c >> 2) * 16 + lc;
    const int ks   = c & 3;
    const float v = (isQ ? q_w : k_w)[drow * kD + ks * 32 + lg * 8 + e];
    const ushort h = bf16_rne(v);
    const ushort lo = bf16_rne(v - bf16_f32(h));
    if (isQ) { ws[WS_QH + j] = h; ws[WS_QL + j] = lo; }
    else     { ws[WS_KH + j] = h; ws[WS_KL + j] = lo; }
  } else if (i < 40960) {  // phi3 (0..4095) / phi2 (4096..8191) fragment planes
    const int j = (i - 32768) & 4095;
    const bool is3 = i < 36864;
    const int nt = j >> 9;
    const int l  = (j >> 3) & 63;
    const int e  = j & 7;
    const int lc = l & 15, lg = l >> 4;
    const int dcol = nt * 16 + lc;
    const int k    = lg * 8 + e;
    const float v = (k < kF) ? (is3 ? p3w : p2w)[dcol * kF + k] : 0.f;
    const ushort h = bf16_rne(v);
    const ushort lo = bf16_rne(v - bf16_f32(h));
    if (is3) { ws[WS_P3H + j] = h; ws[WS_P3L + j] = lo; }
    else     { ws[WS_P2H + j] = h; ws[WS_P2L + j] = lo; }
  } else if (i < 57344) {  // v_w transpose-pack
    const int j = i - 40960;          // 0..16383
    const int j4 = j >> 9;
    const int r  = j & 511;
    const int d  = r >> 2, jj = r & 3;
    float* wsv = (float*)(ws + WS_USH_END);
    wsv[j] = v_w[d * kD + j4 * 4 + jj];
  }
}

// One block (256 threads = 4 waves) per batch element.
__global__ __launch_bounds__(256) void value_net_kernel(
    const float* __restrict__ state,
    const float* __restrict__ phi1_w, const float* __restrict__ phi1_b,
    const float* __restrict__ phi2_b, const float* __restrict__ phi3_b,
    const float* __restrict__ q_b,    const float* __restrict__ k_b,
    const float* __restrict__ v_b,
    const float* __restrict__ final_w,const float* __restrict__ final_b,
    const ushort* __restrict__ wsc,
    float* __restrict__ out)
{
  const int b    = blockIdx.x;
  const int tid  = threadIdx.x;
  const int lane = tid & 63;
  const int wave = tid >> 6;
  const int d    = tid & (kD - 1);
  const int half = tid >> 7;
  const int lc   = lane & 15;   // fragment col
  const int lg   = lane >> 4;   // fragment k-group / row-group

  __shared__ float s_lds[kN][16];                  // state rows, padded 13->16 (zero tail)
  __shared__ __align__(16) ushort h3_hi[kN * kD];  // swizzled split bf16 of h3
  __shared__ __align__(16) ushort h3_lo[kN * kD];
  __shared__ float spart[4][kN];
  __shared__ float w_lds[kN];
  __shared__ float hbar_w[4][kD];
  __shared__ float hbar_lds[kD];
  __shared__ float red[4];

  // ---- stage state rows (coalesced) + zero pad ----
  const float* sb = state + (size_t)b * (kN * kF);
  for (int i = tid; i < kN * kF; i += 256) s_lds[i / kF][i % kF] = sb[i];
  for (int i = tid; i < kN * 3; i += 256) s_lds[i / 3][kF + (i % 3)] = 0.f;
  __syncthreads();

  // ---- A-fragments of state (split bf16), shared by phi3 and phi2 MFMAs ----
  short8 a3h = {0, 0, 0, 0, 0, 0, 0, 0};
  short8 a3l = {0, 0, 0, 0, 0, 0, 0, 0};
  if (lg < 2) {
    const float* p = &s_lds[wave * 16 + lc][lg * 8];
#pragma unroll
    for (int i = 0; i < 8; ++i) {
      float x = p[i];
      ushort hbv = bf16_rne(x);
      a3h[i] = (short)hbv;
      a3l[i] = (short)bf16_rne(x - bf16_f32(hbv));
    }
  }

  // ---- phi3 via MFMA: h3[n][d] = relu(state @ phi3_w^T + b3), split bf16 to LDS ----
#pragma unroll
  for (int nt = 0; nt < 8; ++nt) {
    const int dcol = nt * 16 + lc;
    short8 bh = *(const short8*)&wsc[WS_P3H + nt * 512 + lane * 8];
    short8 bl = *(const short8*)&wsc[WS_P3L + nt * 512 + lane * 8];
    f32x4 a = {0.f, 0.f, 0.f, 0.f};
    a = __builtin_amdgcn_mfma_f32_16x16x32_bf16(a3h, bh, a, 0, 0, 0);
    a = __builtin_amdgcn_mfma_f32_16x16x32_bf16(a3l, bh, a, 0, 0, 0);
    a = __builtin_amdgcn_mfma_f32_16x16x32_bf16(a3h, bl, a, 0, 0, 0);
    const float bias = phi3_b[dcol];
#pragma unroll
    for (int r = 0; r < 4; ++r) {
      const int nw = wave * 16 + lg * 4 + r;
      float v = fmaxf(a[r] + bias, 0.f);
      ushort hbv = bf16_rne(v);
      ushort lbv = bf16_rne(v - bf16_f32(hbv));
      const int idx = (nw * kD + dcol) ^ ((nw & 7) << 3);
      h3_hi[idx] = hbv;
      h3_lo[idx] = lbv;
    }
  }
  __syncthreads();  // h3 ready

  const int dbase = wave * 32;

  // ---- Q pass: qsum[d] = sum_n relu(Q[n][d]+qb), kept in-lane ----
  float qs[2] = {0.f, 0.f};
  {
    const float qbv[2] = {q_b[dbase + lc], q_b[dbase + 16 + lc]};
    short8 bqh[2][4], bql[2][4];
#pragma unroll
    for (int dtl = 0; dtl < 2; ++dtl) {
      const int cb = (wave * 2 + dtl) * 4;
#pragma unroll
      for (int ks = 0; ks < 4; ++ks) {
        bqh[dtl][ks] = *(const short8*)&wsc[WS_QH + (cb + ks) * 512 + lane * 8];
        bql[dtl][ks] = *(const short8*)&wsc[WS_QL + (cb + ks) * 512 + lane * 8];
      }
    }
#pragma unroll
    for (int nt = 0; nt < 4; ++nt) {
      const int row = nt * 16 + lc;
      short8 ah[4], al[4];
#pragma unroll
      for (int ks = 0; ks < 4; ++ks) {
        const int idx = (row * kD + ks * 32 + lg * 8) ^ ((row & 7) << 3);
        ah[ks] = *(const short8*)&h3_hi[idx];
        al[ks] = *(const short8*)&h3_lo[idx];
      }
#pragma unroll
      for (int dtl = 0; dtl < 2; ++dtl) {
        f32x4 acc = {0.f, 0.f, 0.f, 0.f};
#pragma unroll
        for (int ks = 0; ks < 4; ++ks) {
          acc = __builtin_amdgcn_mfma_f32_16x16x32_bf16(ah[ks], bqh[dtl][ks], acc, 0, 0, 0);
          acc = __builtin_amdgcn_mfma_f32_16x16x32_bf16(al[ks], bqh[dtl][ks], acc, 0, 0, 0);
          acc = __builtin_amdgcn_mfma_f32_16x16x32_bf16(ah[ks], bql[dtl][ks], acc, 0, 0, 0);
        }
        float t = 0.f;
#pragma unroll
        for (int r = 0; r < 4; ++r) t += fmaxf(acc[r] + qbv[dtl], 0.f);
        qs[dtl] += t;
      }
    }
  }
#pragma unroll
  for (int dtl = 0; dtl < 2; ++dtl) {
    qs[dtl] += __shfl_xor(qs[dtl], 16, 64);
    qs[dtl] += __shfl_xor(qs[dtl], 32, 64);
  }

  // ---- K pass + score partials ----
  {
    const float kbv[2] = {k_b[dbase + lc], k_b[dbase + 16 + lc]};
    short8 bkh[2][4], bkl[2][4];
#pragma unroll
    for (int dtl = 0; dtl < 2; ++dtl) {
      const int cb = (wave * 2 + dtl) * 4;
#pragma unroll
      for (int ks = 0; ks < 4; ++ks) {
        bkh[dtl][ks] = *(const short8*)&wsc[WS_KH + (cb + ks) * 512 + lane * 8];
        bkl[dtl][ks] = *(const short8*)&wsc[WS_KL + (cb + ks) * 512 + lane * 8];
      }
    }
#pragma unroll
    for (int nt = 0; nt < 4; ++nt) {
      const int row = nt * 16 + lc;
      short8 ah[4], al[4];
#pragma unroll
      for (int ks = 0; ks < 4; ++ks) {
        const int idx = (row * kD + ks * 32 + lg * 8) ^ ((row & 7) << 3);
        ah[ks] = *(const short8*)&h3_hi[idx];
        al[ks] = *(const short8*)&h3_lo[idx];
      }
      float pr[4] = {0.f, 0.f, 0.f, 0.f};
#pragma unroll
      for (int dtl = 0; dtl < 2; ++dtl) {
        f32x4 acc = {0.f, 0.f, 0.f, 0.f};
#pragma unroll
        for (int ks = 0; ks < 4; ++ks) {
          acc = __builtin_amdgcn_mfma_f32_16x16x32_bf16(ah[ks], bkh[dtl][ks], acc, 0, 0, 0);
          acc = __builtin_amdgcn_mfma_f32_16x16x32_bf16(al[ks], bkh[dtl][ks], acc, 0, 0, 0);
          acc = __builtin_amdgcn_mfma_f32_16x16x32_bf16(ah[ks], bkl[dtl][ks], acc, 0, 0, 0);
        }
#pragma unroll
        for (int r = 0; r < 4; ++r)
          pr[r] = fmaf(qs[dtl], fmaxf(acc[r] + kbv[dtl], 0.f), pr[r]);
      }
#pragma unroll
      for (int r = 0; r < 4; ++r) {
        pr[r] += __shfl_xor(pr[r], 1, 64);
        pr[r] += __shfl_xor(pr[r], 2, 64);
        pr[r] += __shfl_xor(pr[r], 4, 64);
        pr[r] += __shfl_xor(pr[r], 8, 64);
      }
      if (lc == 0) {
#pragma unroll
        for (int r = 0; r < 4; ++r) spart[wave][nt * 16 + lg * 4 + r] = pr[r];
      }
    }
  }
  __syncthreads();

  // ---- softmax over the 64 scores (wave 0) ----
  if (wave == 0) {
    const int m = lane;
    float sc = spart[0][m] + spart[1][m] + spart[2][m] + spart[3][m];
    sc = fmaxf(sc * kTemp, 0.f);
    float mx = sc;
#pragma unroll
    for (int off = 32; off > 0; off >>= 1) mx = fmaxf(mx, __shfl_xor(mx, off, 64));
    float e = __expf(sc - mx);
    float s = e;
#pragma unroll
    for (int off = 32; off > 0; off >>= 1) s += __shfl_xor(s, off, 64);
    w_lds[m] = e / s;
  }
  __syncthreads();

  // ---- phi2 via MFMA (epilogue): hbar[d] = sum_n w[n]*relu(h2[n][d]) ----
  {
    float wv[4];
#pragma unroll
    for (int r = 0; r < 4; ++r) wv[r] = w_lds[wave * 16 + lg * 4 + r];
#pragma unroll
    for (int nt = 0; nt < 8; ++nt) {
      const int dcol = nt * 16 + lc;
      short8 bh = *(const short8*)&wsc[WS_P2H + nt * 512 + lane * 8];
      short8 bl = *(const short8*)&wsc[WS_P2L + nt * 512 + lane * 8];
      f32x4 a = {0.f, 0.f, 0.f, 0.f};
      a = __builtin_amdgcn_mfma_f32_16x16x32_bf16(a3h, bh, a, 0, 0, 0);
      a = __builtin_amdgcn_mfma_f32_16x16x32_bf16(a3l, bh, a, 0, 0, 0);
      a = __builtin_amdgcn_mfma_f32_16x16x32_bf16(a3h, bl, a, 0, 0, 0);
      const float b2 = phi2_b[dcol];
      float hp = 0.f;
#pragma unroll
      for (int r = 0; r < 4; ++r) hp = fmaf(wv[r], fmaxf(a[r] + b2, 0.f), hp);
      hp += __shfl_xor(hp, 16, 64);
      hp += __shfl_xor(hp, 32, 64);
      if (lg == 0) hbar_w[wave][dcol] = hp;
    }
  }
  __syncthreads();
  if (half == 0) hbar_lds[d] = hbar_w[0][d] + hbar_w[1][d] + hbar_w[2][d] + hbar_w[3][d];
  __syncthreads();

  // ---- e_g = v_w . hbar + v_b; value = final_w . [e_g, e_h] + final_b ----
  float contrib;
  {
    const float* wsv = (const float*)(wsc + WS_USH_END);
    float egp = 0.f;
#pragma unroll
    for (int j4 = 0; j4 < 16; ++j4) {
      float4 w4 = *(const float4*)&wsv[(half * 16 + j4) * 512 + d * 4];
      float4 h4 = *(const float4*)&hbar_lds[half * 64 + j4 * 4];
      egp = fmaf(w4.x, h4.x, egp);
      egp = fmaf(w4.y, h4.y, egp);
      egp = fmaf(w4.z, h4.z, egp);
      egp = fmaf(w4.w, h4.w, egp);
    }
    if (half == 0) egp += v_b[d];
    contrib = final_w[d] * egp;
    if (half == 0) {
      float eh = phi1_b[d];
#pragma unroll
      for (int j = 0; j < kSelf; ++j) eh = fmaf(phi1_w[d * kSelf + j], s_lds[0][j], eh);
      contrib = fmaf(final_w[kD + d], eh, contrib);
    }
  }
#pragma unroll
  for (int off = 32; off > 0; off >>= 1) contrib += __shfl_xor(contrib, off, 64);
  if (lane == 0) red[wave] = contrib;
  __syncthreads();
  if (tid == 0) out[b] = red[0] + red[1] + red[2] + red[3] + final_b[0];
}

extern "C" void kernel_launch(void* const* d_in, const int* in_sizes, int n_in,
                              void* d_out, int out_size, void* d_ws, size_t ws_size,
                              hipStream_t stream) {
  const float* state   = (const float*)d_in[0];
  const float* phi1_w  = (const float*)d_in[1];
  const float* phi1_b  = (const float*)d_in[2];
  const float* phi2_w  = (const float*)d_in[3];
  const float* phi2_b  = (const float*)d_in[4];
  const float* phi3_w  = (const float*)d_in[5];
  const float* phi3_b  = (const float*)d_in[6];
  const float* q_w     = (const float*)d_in[7];
  const float* q_b     = (const float*)d_in[8];
  const float* k_w     = (const float*)d_in[9];
  const float* k_b     = (const float*)d_in[10];
  const float* v_w     = (const float*)d_in[11];
  const float* v_b     = (const float*)d_in[12];
  const float* final_w = (const float*)d_in[13];
  const float* final_b = (const float*)d_in[14];
  float* out = (float*)d_out;
  ushort* ws = (ushort*)d_ws;

  prep_kernel<<<dim3(224), dim3(256), 0, stream>>>(q_w, k_w, phi3_w, phi2_w, v_w, ws);

  const int batches = in_sizes[0] / (kN * kF);  // 4096
  value_net_kernel<<<dim3(batches), dim3(256), 0, stream>>>(
      state, phi1_w, phi1_b, phi2_b, phi3_b,
      q_b, k_b, v_b, final_w, final_b, ws, out);
}

// Round 6
// 79.000 us; speedup vs baseline: 6.2138x; 1.3273x over previous
//
#include <hip/hip_runtime.h>
#include <math.h>

typedef __attribute__((ext_vector_type(8))) short short8;
typedef __attribute__((ext_vector_type(4))) float f32x4;
using half8 = __attribute__((ext_vector_type(8))) _Float16;

constexpr int kN = 64;     // nodes per batch
constexpr int kF = 13;     // features
constexpr int kD = 128;    // hidden dim
constexpr int kSelf = 6;
constexpr float kTemp = 0.08838834764831845f;   // 1/sqrt(128)
constexpr float kLoScale = 4096.f;              // weight-lo plane scale (avoids f16 denormals)
constexpr float kLoInv   = 1.0f / 4096.f;

// ws layout (ushort element offsets). All weight planes FRAGMENT-PACKED in
// lane order: chunk = 512 ushorts (64 lanes x 8 f16 = 1KB), wave load =
// base + lane*16B -> one coalesced transaction.
// Q/K planes: 32 chunks, chunk c=(dtile<<2)|ks, lane l=(lg<<4)|lc, elem e:
//   W[dtile*16+lc][ks*32+lg*8+e]   (hi plane: f16(v); lo plane: f16((v-hi)*4096))
// phi planes: 8 chunks (nt): P[nt*16+lc][lg*8+e], k>=13 zero-padded
// v plane (f32): 32 chunks of 512 f32, chunk j4: entry d*4+jj = v_w[d][j4*4+jj]
constexpr int WS_QH  = 0;
constexpr int WS_QL  = 16384;
constexpr int WS_KH  = 32768;
constexpr int WS_KL  = 49152;
constexpr int WS_P3H = 65536;
constexpr int WS_P3L = 69632;
constexpr int WS_P2H = 73728;
constexpr int WS_P2L = 77824;
constexpr int WS_USH_END = 81920;   // then 16384 f32 for v_w -> total 229376 B

__device__ __forceinline__ ushort f16h(float v) {
  _Float16 h = (_Float16)v;
  return __builtin_bit_cast(unsigned short, h);
}
__device__ __forceinline__ float f16f(ushort b) {
  return (float)__builtin_bit_cast(_Float16, b);
}
__device__ __forceinline__ half8 ld_h8(const ushort* p) {
  return __builtin_bit_cast(half8, *(const short8*)p);
}
#define MFMA16(a, b, c) __builtin_amdgcn_mfma_f32_16x16x32_f16((a), (b), (c), 0, 0, 0)

__global__ __launch_bounds__(256) void prep_kernel(
    const float* __restrict__ q_w, const float* __restrict__ k_w,
    const float* __restrict__ p3w, const float* __restrict__ p2w,
    const float* __restrict__ v_w,
    ushort* __restrict__ ws)
{
  const int i = blockIdx.x * 256 + threadIdx.x;
  if (i < 32768) {            // Q / K fragment planes
    const int j = i & 16383;
    const bool isQ = i < 16384;
    const int c  = j >> 9;
    const int l  = (j >> 3) & 63;
    const int e  = j & 7;
    const int lc = l & 15, lg = l >> 4;
    const int drow = (c >> 2) * 16 + lc;
    const int ks   = c & 3;
    const float v = (isQ ? q_w : k_w)[drow * kD + ks * 32 + lg * 8 + e];
    const ushort h  = f16h(v);
    const ushort lo = f16h((v - f16f(h)) * kLoScale);
    if (isQ) { ws[WS_QH + j] = h; ws[WS_QL + j] = lo; }
    else     { ws[WS_KH + j] = h; ws[WS_KL + j] = lo; }
  } else if (i < 40960) {     // phi3 / phi2 fragment planes
    const int j = (i - 32768) & 4095;
    const bool is3 = i < 36864;
    const int nt = j >> 9;
    const int l  = (j >> 3) & 63;
    const int e  = j & 7;
    const int lc = l & 15, lg = l >> 4;
    const int dcol = nt * 16 + lc;
    const int k    = lg * 8 + e;
    const float v = (k < kF) ? (is3 ? p3w : p2w)[dcol * kF + k] : 0.f;
    const ushort h  = f16h(v);
    const ushort lo = f16h((v - f16f(h)) * kLoScale);
    if (is3) { ws[WS_P3H + j] = h; ws[WS_P3L + j] = lo; }
    else     { ws[WS_P2H + j] = h; ws[WS_P2L + j] = lo; }
  } else if (i < 57344) {     // v_w transpose-pack (f32)
    const int j = i - 40960;
    const int j4 = j >> 9;
    const int r  = j & 511;
    const int d  = r >> 2, jj = r & 3;
    ((float*)(ws + WS_USH_END))[j] = v_w[d * kD + j4 * 4 + jj];
  }
}

// One block (256 threads = 4 waves) per batch element.
// Structure is identical to the round-4 kernel (proven deterministic); only the
// numeric format changed: f16 activations + split-f16 weights (2 MFMA / product).
__global__ __launch_bounds__(256) void value_net_kernel(
    const float* __restrict__ state,
    const float* __restrict__ phi1_w, const float* __restrict__ phi1_b,
    const float* __restrict__ phi2_b, const float* __restrict__ phi3_b,
    const float* __restrict__ q_b,    const float* __restrict__ k_b,
    const float* __restrict__ v_b,
    const float* __restrict__ final_w,const float* __restrict__ final_b,
    const ushort* __restrict__ wsc,
    float* __restrict__ out)
{
  const int b    = blockIdx.x;
  const int tid  = threadIdx.x;
  const int lane = tid & 63;
  const int wave = tid >> 6;
  const int d    = tid & (kD - 1);
  const int half = tid >> 7;
  const int lc   = lane & 15;   // fragment col / row-in-tile
  const int lg   = lane >> 4;   // fragment k-octet / row-group

  __shared__ float s_lds[kN][16];                 // state rows padded 13->16 (zero tail)
  __shared__ __align__(16) ushort h3[kN * kD];    // f16 bits, XOR-swizzled
  __shared__ float spart[4][kN];
  __shared__ float w_lds[kN];
  __shared__ float hbar_w[4][kD];
  __shared__ float hbar_lds[kD];
  __shared__ float red[4];

  // ---- stage state rows (coalesced) + zero pad ----
  const float* sb = state + (size_t)b * (kN * kF);
  for (int i = tid; i < kN * kF; i += 256) s_lds[i / kF][i % kF] = sb[i];
  for (int i = tid; i < kN * 3; i += 256) s_lds[i / 3][kF + (i % 3)] = 0.f;
  __syncthreads();

  // ---- A-fragment of state (f16), shared by phi3 and phi2 ----
  short8 a3s = {0, 0, 0, 0, 0, 0, 0, 0};
  if (lg < 2) {
    const float* p = &s_lds[wave * 16 + lc][lg * 8];
#pragma unroll
    for (int i = 0; i < 8; ++i) a3s[i] = (short)f16h(p[i]);
  }
  const half8 a3 = __builtin_bit_cast(half8, a3s);

  // ---- phi3 via MFMA: h3[n][d] = relu(state @ phi3_w^T + b3) -> f16 LDS ----
#pragma unroll
  for (int nt = 0; nt < 8; ++nt) {
    const int dcol = nt * 16 + lc;
    half8 bh = ld_h8(&wsc[WS_P3H + nt * 512 + lane * 8]);
    half8 bl = ld_h8(&wsc[WS_P3L + nt * 512 + lane * 8]);
    f32x4 aH = {0.f, 0.f, 0.f, 0.f}, aL = {0.f, 0.f, 0.f, 0.f};
    aH = MFMA16(a3, bh, aH);
    aL = MFMA16(a3, bl, aL);
    const float bias = phi3_b[dcol];
#pragma unroll
    for (int r = 0; r < 4; ++r) {
      const int nw = wave * 16 + lg * 4 + r;
      float v = fmaxf(fmaf(kLoInv, aL[r], aH[r]) + bias, 0.f);
      h3[(nw * kD + dcol) ^ ((nw & 7) << 3)] = f16h(v);
    }
  }
  __syncthreads();  // h3 ready

  const int dbase = wave * 32;

  // ---- Q pass: qsum[d] = sum_n relu(Q[n][d]+qb), kept in-lane ----
  float qs[2] = {0.f, 0.f};
  {
    const float qbv[2] = {q_b[dbase + lc], q_b[dbase + 16 + lc]};
    half8 bqh[2][4], bql[2][4];
#pragma unroll
    for (int dtl = 0; dtl < 2; ++dtl) {
      const int cb = (wave * 2 + dtl) * 4;
#pragma unroll
      for (int ks = 0; ks < 4; ++ks) {
        bqh[dtl][ks] = ld_h8(&wsc[WS_QH + (cb + ks) * 512 + lane * 8]);
        bql[dtl][ks] = ld_h8(&wsc[WS_QL + (cb + ks) * 512 + lane * 8]);
      }
    }
#pragma unroll
    for (int nt = 0; nt < 4; ++nt) {
      const int row = nt * 16 + lc;
      const int rb  = row * kD;
      const int swz = (row & 7) << 3;
      half8 ah[4];
#pragma unroll
      for (int ks = 0; ks < 4; ++ks)
        ah[ks] = ld_h8(&h3[(rb + ks * 32 + lg * 8) ^ swz]);
#pragma unroll
      for (int dtl = 0; dtl < 2; ++dtl) {
        f32x4 aH = {0.f, 0.f, 0.f, 0.f}, aL = {0.f, 0.f, 0.f, 0.f};
#pragma unroll
        for (int ks = 0; ks < 4; ++ks) {
          aH = MFMA16(ah[ks], bqh[dtl][ks], aH);
          aL = MFMA16(ah[ks], bql[dtl][ks], aL);
        }
#pragma unroll
        for (int r = 0; r < 4; ++r)
          qs[dtl] += fmaxf(fmaf(kLoInv, aL[r], aH[r]) + qbv[dtl], 0.f);
      }
    }
  }
#pragma unroll
  for (int dtl = 0; dtl < 2; ++dtl) {
    qs[dtl] += __shfl_xor(qs[dtl], 16, 64);
    qs[dtl] += __shfl_xor(qs[dtl], 32, 64);
  }

  // ---- K pass + score partials (round-4 structure: C[node][d], bpermute tree) ----
  {
    const float kbv[2] = {k_b[dbase + lc], k_b[dbase + 16 + lc]};
    half8 bkh[2][4], bkl[2][4];
#pragma unroll
    for (int dtl = 0; dtl < 2; ++dtl) {
      const int cb = (wave * 2 + dtl) * 4;
#pragma unroll
      for (int ks = 0; ks < 4; ++ks) {
        bkh[dtl][ks] = ld_h8(&wsc[WS_KH + (cb + ks) * 512 + lane * 8]);
        bkl[dtl][ks] = ld_h8(&wsc[WS_KL + (cb + ks) * 512 + lane * 8]);
      }
    }
#pragma unroll
    for (int nt = 0; nt < 4; ++nt) {
      const int row = nt * 16 + lc;
      const int rb  = row * kD;
      const int swz = (row & 7) << 3;
      half8 ah[4];
#pragma unroll
      for (int ks = 0; ks < 4; ++ks)
        ah[ks] = ld_h8(&h3[(rb + ks * 32 + lg * 8) ^ swz]);
      float pr[4] = {0.f, 0.f, 0.f, 0.f};
#pragma unroll
      for (int dtl = 0; dtl < 2; ++dtl) {
        f32x4 aH = {0.f, 0.f, 0.f, 0.f}, aL = {0.f, 0.f, 0.f, 0.f};
#pragma unroll
        for (int ks = 0; ks < 4; ++ks) {
          aH = MFMA16(ah[ks], bkh[dtl][ks], aH);
          aL = MFMA16(ah[ks], bkl[dtl][ks], aL);
        }
#pragma unroll
        for (int r = 0; r < 4; ++r)
          pr[r] = fmaf(qs[dtl], fmaxf(fmaf(kLoInv, aL[r], aH[r]) + kbv[dtl], 0.f), pr[r]);
      }
#pragma unroll
      for (int r = 0; r < 4; ++r) {
        pr[r] += __shfl_xor(pr[r], 1, 64);
        pr[r] += __shfl_xor(pr[r], 2, 64);
        pr[r] += __shfl_xor(pr[r], 4, 64);
        pr[r] += __shfl_xor(pr[r], 8, 64);
      }
      if (lc == 0) {
#pragma unroll
        for (int r = 0; r < 4; ++r) spart[wave][nt * 16 + lg * 4 + r] = pr[r];
      }
    }
  }
  __syncthreads();

  // ---- softmax over the 64 scores (wave 0) ----
  if (wave == 0) {
    const int m = lane;
    float sc = spart[0][m] + spart[1][m] + spart[2][m] + spart[3][m];
    sc = fmaxf(sc * kTemp, 0.f);
    float mx = sc;
#pragma unroll
    for (int off = 32; off > 0; off >>= 1) mx = fmaxf(mx, __shfl_xor(mx, off, 64));
    float e = __expf(sc - mx);
    float s = e;
#pragma unroll
    for (int off = 32; off > 0; off >>= 1) s += __shfl_xor(s, off, 64);
    w_lds[m] = e / s;
  }
  __syncthreads();

  // ---- phi2 via MFMA: hbar[d] = sum_n w[n]*relu(h2[n][d]) ----
  {
    float wv[4];
#pragma unroll
    for (int r = 0; r < 4; ++r) wv[r] = w_lds[wave * 16 + lg * 4 + r];
#pragma unroll
    for (int nt = 0; nt < 8; ++nt) {
      const int dcol = nt * 16 + lc;
      half8 bh = ld_h8(&wsc[WS_P2H + nt * 512 + lane * 8]);
      half8 bl = ld_h8(&wsc[WS_P2L + nt * 512 + lane * 8]);
      f32x4 aH = {0.f, 0.f, 0.f, 0.f}, aL = {0.f, 0.f, 0.f, 0.f};
      aH = MFMA16(a3, bh, aH);
      aL = MFMA16(a3, bl, aL);
      const float b2 = phi2_b[dcol];
      float hp = 0.f;
#pragma unroll
      for (int r = 0; r < 4; ++r)
        hp = fmaf(wv[r], fmaxf(fmaf(kLoInv, aL[r], aH[r]) + b2, 0.f), hp);
      hp += __shfl_xor(hp, 16, 64);
      hp += __shfl_xor(hp, 32, 64);
      if (lg == 0) hbar_w[wave][dcol] = hp;
    }
  }
  __syncthreads();
  if (half == 0) hbar_lds[d] = hbar_w[0][d] + hbar_w[1][d] + hbar_w[2][d] + hbar_w[3][d];
  __syncthreads();

  // ---- e_g = v_w . hbar + v_b; value = final_w . [e_g, e_h] + final_b ----
  float contrib;
  {
    const float* wsv = (const float*)(wsc + WS_USH_END);
    float egp = 0.f;
#pragma unroll
    for (int j4 = 0; j4 < 16; ++j4) {
      float4 w4 = *(const float4*)&wsv[(half * 16 + j4) * 512 + d * 4];
      float4 h4 = *(const float4*)&hbar_lds[half * 64 + j4 * 4];
      egp = fmaf(w4.x, h4.x, egp);
      egp = fmaf(w4.y, h4.y, egp);
      egp = fmaf(w4.z, h4.z, egp);
      egp = fmaf(w4.w, h4.w, egp);
    }
    if (half == 0) egp += v_b[d];
    contrib = final_w[d] * egp;
    if (half == 0) {
      float eh = phi1_b[d];
#pragma unroll
      for (int j = 0; j < kSelf; ++j) eh = fmaf(phi1_w[d * kSelf + j], s_lds[0][j], eh);
      contrib = fmaf(final_w[kD + d], eh, contrib);
    }
  }
#pragma unroll
  for (int off = 32; off > 0; off >>= 1) contrib += __shfl_xor(contrib, off, 64);
  if (lane == 0) red[wave] = contrib;
  __syncthreads();
  if (tid == 0) out[b] = red[0] + red[1] + red[2] + red[3] + final_b[0];
}

extern "C" void kernel_launch(void* const* d_in, const int* in_sizes, int n_in,
                              void* d_out, int out_size, void* d_ws, size_t ws_size,
                              hipStream_t stream) {
  const float* state   = (const float*)d_in[0];
  const float* phi1_w  = (const float*)d_in[1];
  const float* phi1_b  = (const float*)d_in[2];
  const float* phi2_w  = (const float*)d_in[3];
  const float* phi2_b  = (const float*)d_in[4];
  const float* phi3_w  = (const float*)d_in[5];
  const float* phi3_b  = (const float*)d_in[6];
  const float* q_w     = (const float*)d_in[7];
  const float* q_b     = (const float*)d_in[8];
  const float* k_w     = (const float*)d_in[9];
  const float* k_b     = (const float*)d_in[10];
  const float* v_w     = (const float*)d_in[11];
  const float* v_b     = (const float*)d_in[12];
  const float* final_w = (const float*)d_in[13];
  const float* final_b = (const float*)d_in[14];
  float* out = (float*)d_out;
  ushort* ws = (ushort*)d_ws;

  prep_kernel<<<dim3(224), dim3(256), 0, stream>>>(q_w, k_w, phi3_w, phi2_w, v_w, ws);

  const int batches = in_sizes[0] / (kN * kF);  // 4096
  value_net_kernel<<<dim3(batches), dim3(256), 0, stream>>>(
      state, phi1_w, phi1_b, phi2_b, phi3_b,
      q_b, k_b, v_b, final_w, final_b, ws, out);
}

// Round 7
// 64.468 us; speedup vs baseline: 7.6146x; 1.2254x over previous
//
#include <hip/hip_runtime.h>
#include <math.h>

typedef __attribute__((ext_vector_type(8))) short short8;
typedef __attribute__((ext_vector_type(4))) float f32x4;
using half8 = __attribute__((ext_vector_type(8))) _Float16;

constexpr int kN = 64;     // nodes per batch
constexpr int kF = 13;     // features
constexpr int kD = 128;    // hidden dim
constexpr int kSelf = 6;
constexpr float kTemp = 0.08838834764831845f;   // 1/sqrt(128)
constexpr float kLoScale = 4096.f;              // weight-lo plane scale (avoids f16 denormals)
constexpr float kLoInv   = 1.0f / 4096.f;

// ws layout (ushort element offsets). Weight planes FRAGMENT-PACKED in lane
// order: chunk = 512 ushorts (64 lanes x 8 f16 = 1KB); wave load = base+lane*16B.
// Q/K planes (split f16 hi/lo): 32 chunks, chunk c=(dtile<<2)|ks, lane l=(lg<<4)|lc:
//   W[dtile*16+lc][ks*32+lg*8+e]
// phi planes (hi only): 8 chunks (nt): P[nt*16+lc][lg*8+e], k>=13 zero-padded
// f32 region at ushort offset WS_F32:
//   [0..127]  fvec  = v_w^T @ final_w[:128]
//   [128..133] gvec = phi1_w^T @ final_w[128:]
//   [134]     const = final_b + final_w[:128].v_b + final_w[128:].phi1_b
constexpr int WS_QH  = 0;
constexpr int WS_QL  = 16384;
constexpr int WS_KH  = 32768;
constexpr int WS_KL  = 49152;
constexpr int WS_P3  = 65536;
constexpr int WS_P2  = 69632;
constexpr int WS_F32 = 73728;   // total ws: 147456 + 540 bytes

__device__ __forceinline__ ushort f16h(float v) {
  _Float16 h = (_Float16)v;
  return __builtin_bit_cast(unsigned short, h);
}
__device__ __forceinline__ float f16f(ushort b) {
  return (float)__builtin_bit_cast(_Float16, b);
}
__device__ __forceinline__ half8 ld_h8(const ushort* p) {
  return __builtin_bit_cast(half8, *(const short8*)p);
}
#define MFMA16(a, b, c) __builtin_amdgcn_mfma_f32_16x16x32_f16((a), (b), (c), 0, 0, 0)

__global__ __launch_bounds__(256) void prep_kernel(
    const float* __restrict__ q_w, const float* __restrict__ k_w,
    const float* __restrict__ p3w, const float* __restrict__ p2w,
    const float* __restrict__ v_w, const float* __restrict__ phi1_w,
    const float* __restrict__ phi1_b, const float* __restrict__ v_b,
    const float* __restrict__ final_w, const float* __restrict__ final_b,
    ushort* __restrict__ ws)
{
  const int i = blockIdx.x * 256 + threadIdx.x;
  if (i < 32768) {            // Q / K split fragment planes
    const int j = i & 16383;
    const bool isQ = i < 16384;
    const int c  = j >> 9;
    const int l  = (j >> 3) & 63;
    const int e  = j & 7;
    const int lc = l & 15, lg = l >> 4;
    const int drow = (c >> 2) * 16 + lc;
    const int ks   = c & 3;
    const float v = (isQ ? q_w : k_w)[drow * kD + ks * 32 + lg * 8 + e];
    const ushort h  = f16h(v);
    const ushort lo = f16h((v - f16f(h)) * kLoScale);
    if (isQ) { ws[WS_QH + j] = h; ws[WS_QL + j] = lo; }
    else     { ws[WS_KH + j] = h; ws[WS_KL + j] = lo; }
  } else if (i < 40960) {     // phi3 / phi2 hi-only fragment planes
    const int j = (i - 32768) & 4095;
    const bool is3 = i < 36864;
    const int nt = j >> 9;
    const int l  = (j >> 3) & 63;
    const int e  = j & 7;
    const int lc = l & 15, lg = l >> 4;
    const int dcol = nt * 16 + lc;
    const int k    = lg * 8 + e;
    const float v = (k < kF) ? (is3 ? p3w : p2w)[dcol * kF + k] : 0.f;
    ws[(is3 ? WS_P3 : WS_P2) + j] = f16h(v);
  } else if (i < 41088) {     // fvec[j] = sum_d final_w[d] * v_w[d][j]
    const int j = i - 40960;
    float acc = 0.f;
    for (int d2 = 0; d2 < kD; ++d2) acc = fmaf(final_w[d2], v_w[d2 * kD + j], acc);
    ((float*)(ws + WS_F32))[j] = acc;
  } else if (i < 41094) {     // gvec[j] = sum_d final_w[128+d] * phi1_w[d][j]
    const int j = i - 41088;
    float acc = 0.f;
    for (int d2 = 0; d2 < kD; ++d2) acc = fmaf(final_w[kD + d2], phi1_w[d2 * kSelf + j], acc);
    ((float*)(ws + WS_F32))[128 + j] = acc;
  } else if (i == 41094) {    // const
    float acc = final_b[0];
    for (int d2 = 0; d2 < kD; ++d2) acc = fmaf(final_w[d2], v_b[d2], acc);
    for (int d2 = 0; d2 < kD; ++d2) acc = fmaf(final_w[kD + d2], phi1_b[d2], acc);
    ((float*)(ws + WS_F32))[134] = acc;
  }
}

// One block (256 threads = 4 waves) per batch element.
// Sync skeleton identical to round-6 (proven deterministic): 5 barriers.
__global__ __launch_bounds__(256) void value_net_kernel(
    const float* __restrict__ state,
    const float* __restrict__ phi2_b, const float* __restrict__ phi3_b,
    const float* __restrict__ q_b,    const float* __restrict__ k_b,
    const ushort* __restrict__ wsc,
    float* __restrict__ out)
{
  const int b    = blockIdx.x;
  const int tid  = threadIdx.x;
  const int lane = tid & 63;
  const int wave = tid >> 6;
  const int lc   = lane & 15;   // fragment col / row-in-tile
  const int lg   = lane >> 4;   // fragment k-octet / row-group

  __shared__ float s_lds[kN][16];                 // state rows padded 13->16 (zero tail)
  __shared__ __align__(16) ushort h3[kN * kD];    // f16 bits, XOR-swizzled
  __shared__ float fvec_lds[kD];
  __shared__ float spart[4][kN];
  __shared__ float w_lds[kN];
  __shared__ float red[4];

  // ---- stage state rows (coalesced) + zero pad + fvec ----
  const float* sb = state + (size_t)b * (kN * kF);
  for (int i = tid; i < kN * kF; i += 256) s_lds[i / kF][i % kF] = sb[i];
  for (int i = tid; i < kN * 3; i += 256) s_lds[i / 3][kF + (i % 3)] = 0.f;
  if (tid < kD) fvec_lds[tid] = ((const float*)(wsc + WS_F32))[tid];
  __syncthreads();

  // ---- A-fragment of state (f16), shared by phi3 and phi2 ----
  short8 a3s = {0, 0, 0, 0, 0, 0, 0, 0};
  if (lg < 2) {
    const float* p = &s_lds[wave * 16 + lc][lg * 8];
#pragma unroll
    for (int i = 0; i < 8; ++i) a3s[i] = (short)f16h(p[i]);
  }
  const half8 a3 = __builtin_bit_cast(half8, a3s);

  // ---- phi3 via MFMA (hi-only): h3[n][d] = relu(state @ phi3_w^T + b3) -> f16 LDS ----
#pragma unroll
  for (int nt = 0; nt < 8; ++nt) {
    const int dcol = nt * 16 + lc;
    half8 bh = ld_h8(&wsc[WS_P3 + nt * 512 + lane * 8]);
    f32x4 aH = {0.f, 0.f, 0.f, 0.f};
    aH = MFMA16(a3, bh, aH);
    const float bias = phi3_b[dcol];
#pragma unroll
    for (int r = 0; r < 4; ++r) {
      const int nw = wave * 16 + lg * 4 + r;
      float v = fmaxf(aH[r] + bias, 0.f);
      h3[(nw * kD + dcol) ^ ((nw & 7) << 3)] = f16h(v);
    }
  }
  __syncthreads();  // h3 ready

  const int dbase = wave * 32;

  // ---- Q pass (split f16): qsum[d] = sum_n relu(Q[n][d]+qb), kept in-lane ----
  float qs[2] = {0.f, 0.f};
  {
    const float qbv[2] = {q_b[dbase + lc], q_b[dbase + 16 + lc]};
    half8 bqh[2][4], bql[2][4];
#pragma unroll
    for (int dtl = 0; dtl < 2; ++dtl) {
      const int cb = (wave * 2 + dtl) * 4;
#pragma unroll
      for (int ks = 0; ks < 4; ++ks) {
        bqh[dtl][ks] = ld_h8(&wsc[WS_QH + (cb + ks) * 512 + lane * 8]);
        bql[dtl][ks] = ld_h8(&wsc[WS_QL + (cb + ks) * 512 + lane * 8]);
      }
    }
#pragma unroll
    for (int nt = 0; nt < 4; ++nt) {
      const int row = nt * 16 + lc;
      const int rb  = row * kD;
      const int swz = (row & 7) << 3;
      half8 ah[4];
#pragma unroll
      for (int ks = 0; ks < 4; ++ks)
        ah[ks] = ld_h8(&h3[(rb + ks * 32 + lg * 8) ^ swz]);
#pragma unroll
      for (int dtl = 0; dtl < 2; ++dtl) {
        f32x4 aH = {0.f, 0.f, 0.f, 0.f}, aL = {0.f, 0.f, 0.f, 0.f};
#pragma unroll
        for (int ks = 0; ks < 4; ++ks) {
          aH = MFMA16(ah[ks], bqh[dtl][ks], aH);
          aL = MFMA16(ah[ks], bql[dtl][ks], aL);
        }
#pragma unroll
        for (int r = 0; r < 4; ++r)
          qs[dtl] += fmaxf(fmaf(kLoInv, aL[r], aH[r]) + qbv[dtl], 0.f);
      }
    }
  }
#pragma unroll
  for (int dtl = 0; dtl < 2; ++dtl) {
    qs[dtl] += __shfl_xor(qs[dtl], 16, 64);
    qs[dtl] += __shfl_xor(qs[dtl], 32, 64);
  }

  // ---- K pass (split f16) + score partials (R6 structure) ----
  {
    const float kbv[2] = {k_b[dbase + lc], k_b[dbase + 16 + lc]};
    half8 bkh[2][4], bkl[2][4];
#pragma unroll
    for (int dtl = 0; dtl < 2; ++dtl) {
      const int cb = (wave * 2 + dtl) * 4;
#pragma unroll
      for (int ks = 0; ks < 4; ++ks) {
        bkh[dtl][ks] = ld_h8(&wsc[WS_KH + (cb + ks) * 512 + lane * 8]);
        bkl[dtl][ks] = ld_h8(&wsc[WS_KL + (cb + ks) * 512 + lane * 8]);
      }
    }
#pragma unroll
    for (int nt = 0; nt < 4; ++nt) {
      const int row = nt * 16 + lc;
      const int rb  = row * kD;
      const int swz = (row & 7) << 3;
      half8 ah[4];
#pragma unroll
      for (int ks = 0; ks < 4; ++ks)
        ah[ks] = ld_h8(&h3[(rb + ks * 32 + lg * 8) ^ swz]);
      float pr[4] = {0.f, 0.f, 0.f, 0.f};
#pragma unroll
      for (int dtl = 0; dtl < 2; ++dtl) {
        f32x4 aH = {0.f, 0.f, 0.f, 0.f}, aL = {0.f, 0.f, 0.f, 0.f};
#pragma unroll
        for (int ks = 0; ks < 4; ++ks) {
          aH = MFMA16(ah[ks], bkh[dtl][ks], aH);
          aL = MFMA16(ah[ks], bkl[dtl][ks], aL);
        }
#pragma unroll
        for (int r = 0; r < 4; ++r)
          pr[r] = fmaf(qs[dtl], fmaxf(fmaf(kLoInv, aL[r], aH[r]) + kbv[dtl], 0.f), pr[r]);
      }
#pragma unroll
      for (int r = 0; r < 4; ++r) {
        pr[r] += __shfl_xor(pr[r], 1, 64);
        pr[r] += __shfl_xor(pr[r], 2, 64);
        pr[r] += __shfl_xor(pr[r], 4, 64);
        pr[r] += __shfl_xor(pr[r], 8, 64);
      }
      if (lc == 0) {
#pragma unroll
        for (int r = 0; r < 4; ++r) spart[wave][nt * 16 + lg * 4 + r] = pr[r];
      }
    }
  }
  __syncthreads();

  // ---- softmax over the 64 scores (wave 0) ----
  if (wave == 0) {
    const int m = lane;
    float sc = spart[0][m] + spart[1][m] + spart[2][m] + spart[3][m];
    sc = fmaxf(sc * kTemp, 0.f);
    float mx = sc;
#pragma unroll
    for (int off = 32; off > 0; off >>= 1) mx = fmaxf(mx, __shfl_xor(mx, off, 64));
    float e = __expf(sc - mx);
    float s = e;
#pragma unroll
    for (int off = 32; off > 0; off >>= 1) s += __shfl_xor(s, off, 64);
    w_lds[m] = e / s;
  }
  __syncthreads();

  // ---- phi2 (hi-only) + fused final dot: facc = sum_nt fvec[dcol]*hp ----
  float facc = 0.f;
  {
    float wv[4];
#pragma unroll
    for (int r = 0; r < 4; ++r) wv[r] = w_lds[wave * 16 + lg * 4 + r];
#pragma unroll
    for (int nt = 0; nt < 8; ++nt) {
      const int dcol = nt * 16 + lc;
      half8 bh = ld_h8(&wsc[WS_P2 + nt * 512 + lane * 8]);
      f32x4 aH = {0.f, 0.f, 0.f, 0.f};
      aH = MFMA16(a3, bh, aH);
      const float b2 = phi2_b[dcol];
      float hp = 0.f;
#pragma unroll
      for (int r = 0; r < 4; ++r)
        hp = fmaf(wv[r], fmaxf(aH[r] + b2, 0.f), hp);
      facc = fmaf(fvec_lds[dcol], hp, facc);
    }
  }
  // reduce facc over the wave, then across waves
#pragma unroll
  for (int off = 32; off > 0; off >>= 1) facc += __shfl_xor(facc, off, 64);
  if (lane == 0) red[wave] = facc;
  __syncthreads();
  if (tid == 0) {
    const float* fws = (const float*)(wsc + WS_F32);
    float v = red[0] + red[1] + red[2] + red[3] + fws[134];
#pragma unroll
    for (int j = 0; j < kSelf; ++j) v = fmaf(fws[128 + j], s_lds[0][j], v);
    out[b] = v;
  }
}

extern "C" void kernel_launch(void* const* d_in, const int* in_sizes, int n_in,
                              void* d_out, int out_size, void* d_ws, size_t ws_size,
                              hipStream_t stream) {
  const float* state   = (const float*)d_in[0];
  const float* phi1_w  = (const float*)d_in[1];
  const float* phi1_b  = (const float*)d_in[2];
  const float* phi2_w  = (const float*)d_in[3];
  const float* phi2_b  = (const float*)d_in[4];
  const float* phi3_w  = (const float*)d_in[5];
  const float* phi3_b  = (const float*)d_in[6];
  const float* q_w     = (const float*)d_in[7];
  const float* q_b     = (const float*)d_in[8];
  const float* k_w     = (const float*)d_in[9];
  const float* k_b     = (const float*)d_in[10];
  const float* v_w     = (const float*)d_in[11];
  const float* v_b     = (const float*)d_in[12];
  const float* final_w = (const float*)d_in[13];
  const float* final_b = (const float*)d_in[14];
  float* out = (float*)d_out;
  ushort* ws = (ushort*)d_ws;

  prep_kernel<<<dim3(161), dim3(256), 0, stream>>>(
      q_w, k_w, phi3_w, phi2_w, v_w, phi1_w, phi1_b, v_b, final_w, final_b, ws);

  const int batches = in_sizes[0] / (kN * kF);  // 4096
  value_net_kernel<<<dim3(batches), dim3(256), 0, stream>>>(
      state, phi2_b, phi3_b, q_b, k_b, ws, out);
}